// Round 10
// baseline (119.337 us; speedup 1.0000x reference)
//
#include <hip/hip_runtime.h>
#include <hip/hip_bf16.h>
#include <stdint.h>

// B,C,H,W = 2,64,96,96. Inputs fp32, output fp32.
// Budget (round-8 probe, round-9 confirm): attn 42.3µs, proj ~3µs,
// combine ~8µs, fixed per-iteration harness overhead ~65µs (launch-invariant).
// proj6 (round-9, verbatim): chunked c-loop (16ch, unroll 1) + 4 row-blocks
//        per tile -> ~3µs.
// attn14: 4-wave q-split of attn13. Round-9 attn was TLP-starved: 2.25
//        waves/SIMD, E->P->PV dependency chains -> 34% zero-issue with both
//        pipes under 35%. Wave = (key-half, q-half) = 32q x 32k; per-wave
//        regs ~105 -> 4 waves/SIMD (launch_bounds(256,4)). Same 3-buffer
//        counted-vmcnt schedule (3 gloads/wave/stage -> vmcnt(3)), same
//        XOR-swizzled V LDS, ones-MFMA lsum, XCD remap qt*8+(g*BB+b).
// combine: sum G key-split partials, normalize, + gamma*attn + x.
#define BB 2
#define CC 64
#define PP 9216
#define QTILES 144               // PP/64
#define LOG2E 1.4426950408889634f
// big-constant Schraudolph: low16(E*128 + 16248.665 + 1.5*2^23) = bf16 bits of 2^E
#define SCH_BC 12599160.0f

typedef unsigned short ushort;
typedef __attribute__((ext_vector_type(8))) short short8;
typedef __attribute__((ext_vector_type(4))) float floatx4;
typedef __attribute__((ext_vector_type(4))) int intx4;

__device__ __forceinline__ ushort f2bf(float f) {
    unsigned int u = __float_as_uint(f);
    u = (u + 0x7fffu + ((u >> 16) & 1u)) >> 16;   // RNE
    return (ushort)u;
}

// 2^e0, 2^e1 as packed bf16 pair: add-big-constant Schraudolph (no v_cvt),
// then one v_perm_b32 splices the two low16 halves.
__device__ __forceinline__ unsigned int exp2_pk_bf16(float e0, float e1) {
    const float t0 = fmaf(e0, 128.f, SCH_BC);
    const float t1 = fmaf(e1, 128.f, SCH_BC);
    // result bytes: [t0.b0, t0.b1, t1.b0, t1.b1]
    return __builtin_amdgcn_perm(__float_as_uint(t1), __float_as_uint(t0),
                                 0x05040100u);
}

__device__ __forceinline__ void gload16_lds(const void* g, void* lds_base) {
    __builtin_amdgcn_global_load_lds(
        (const __attribute__((address_space(1))) unsigned int*)g,
        (__attribute__((address_space(3))) unsigned int*)lds_base, 16, 0, 0);
}

// ---------------------------------------------------------------------------
// Kernel 1: QKV projection (round-9 proj6, verbatim). 1152 blocks x 256.
// ---------------------------------------------------------------------------
__global__ __launch_bounds__(256)
void proj6(const float* __restrict__ x,
           const float* __restrict__ Wq, const float* __restrict__ bq,
           const float* __restrict__ Wk, const float* __restrict__ bk,
           const float* __restrict__ Wv, const float* __restrict__ bv,
           ushort* __restrict__ qbuf, ushort* __restrict__ kbuf,
           ushort* __restrict__ vfw)
{
    const int tid = threadIdx.x;
    const int px  = tid & 63;
    const int og  = __builtin_amdgcn_readfirstlane(tid >> 6);  // 0..3, wave-uniform
    const int blk = blockIdx.x;
    const int b     = blk / (4 * QTILES);
    const int rem   = blk % (4 * QTILES);
    const int ptile = rem >> 2;
    const int rq    = rem & 3;
    const int p     = ptile * 64 + px;
    const int r0    = rq * 20 + og * 5;          // first of this thread's 5 rows

    const float* wr[5];
#pragma unroll
    for (int r = 0; r < 5; ++r) {
        const int row = r0 + r;
        wr[r] = (row < 8) ? (Wq + row * 64)
              : (row < 16) ? (Wk + (row - 8) * 64)
              : (Wv + (row - 16) * 64);
    }

    const float* xb = x + (size_t)b * 64 * PP + p;
    float acc[5] = {0.f, 0.f, 0.f, 0.f, 0.f};

#pragma unroll 1
    for (int c0 = 0; c0 < 64; c0 += 16) {
        float xv[16];
#pragma unroll
        for (int i = 0; i < 16; ++i)
            xv[i] = xb[(size_t)(c0 + i) * PP];
#pragma unroll
        for (int i = 0; i < 16; ++i) {
#pragma unroll
            for (int r = 0; r < 5; ++r)
                acc[r] = fmaf(wr[r][c0 + i], xv[i], acc[r]);
        }
    }

#pragma unroll
    for (int r = 0; r < 5; ++r) {
        const int row = r0 + r;
        if (row < 8) {
            const float v = (acc[r] + bq[row]) * LOG2E;
            qbuf[((size_t)b * PP + p) * 8 + row] = f2bf(v);
        } else if (row < 16) {
            const float v = acc[r] + bk[row - 8];
            kbuf[((size_t)b * PP + p) * 8 + (row - 8)] = f2bf(v);
        } else {
            const int co = row - 16;
            const float v = acc[r] + bv[co];
            const int pl = p & 31;     // slot permutation within 32-group
            const int ps = (p & ~31) | ((((pl >> 2) & 3) << 3) | (((pl >> 4) & 1) << 2) | (pl & 3));
            vfw[((size_t)b * 64 + co) * PP + ps] = f2bf(v);
        }
    }
}

// ---------------------------------------------------------------------------
// Kernel 2: LDS-staged MFMA flash attention, 4-wave q-split, 3-buffer
// counted-vmcnt, XCD-partitioned. Grid = QTILES*8 blocks of 256;
// blockIdx = qt*8 + gb, gb = g*BB+b. Wave wid: kh = wid&1 (key half),
// qh2 = wid>>1 (q half); each wave = 32q x 32keys x 64ch.
// Per 9216B buffer: V 8KB (8 groups of 1KB; rows XOR-swizzled: LDS[r][pos]
// = global chunk pos^(r&7)) + K 1KB. 3 buffers; epilogue smerge (16KB)
// overlays bufs 0-1 (final compute reads buf2, disjoint).
// Stage: each wave issues EXACTLY 3 gload_lds (K duplicated by all 4 waves
// -> same bytes, benign; V groups {2*wid, 2*wid+1}); vmcnt(3) at iter top
// proves stage(t) landed for this wave; barrier for all; stage(t+2) writes
// the third buffer (disjoint from both readable ones). Final tile peeled.
// QK: E = mfma(A=K, B=Q) -> D[key][q]; P = Schraudolph bf16 bits = PV
// B-operand (V key-permuted at proj); lsum = ones-row MFMA.
// ---------------------------------------------------------------------------
__global__ __launch_bounds__(256, 4)
void attn14(const ushort* __restrict__ qbuf, const ushort* __restrict__ kbuf,
            const ushort* __restrict__ vfw,
            ushort* __restrict__ accp, float* __restrict__ lsump,
            int keysPerG, int numTiles)
{
    // 0..27648: 3x (V 8KB + K 1KB) | 27648..27904: slsum (2 qh x 32 f32)
    // smerge (16KB f32, [qh2*64+c][32q]) overlays 0..16384 after the loop.
    __shared__ __align__(16) char sbuf[27904];
    float* smerge = (float*)sbuf;
    float* slsum  = (float*)(sbuf + 27648);

    const int tid  = threadIdx.x;
    const int lane = tid & 63;
    const int wid  = tid >> 6;        // 0..3
    const int kh   = wid & 1;         // key half
    const int qh2  = wid >> 1;        // q half
    const int col  = lane & 15;
    const int quad = lane >> 4;

    // XCD-aware decode: consecutive blockIdx round-robin across the 8 XCDs,
    // so gb = blockIdx & 7 pins each (g,b) key-slice to one XCD's L2.
    const int qt = blockIdx.x >> 3;   // 0..143
    const int gb = blockIdx.x & 7;    // 0..7 = g*BB+b
    const int b  = gb % BB;
    const int g  = gb / BB;
    const int q0 = qt * 64 + qh2 * 32;   // this wave's 32 q rows

    const short8 zf = {0, 0, 0, 0, 0, 0, 0, 0};
    const short vone = (short)0x3F80;                 // bf16 1.0
    const short8 vones = {vone, vone, vone, vone, vone, vone, vone, vone};

    // Q fragments (B-operand: B[k=d=quad*8+j][n=q=col]); only quad 0 real.
    short8 qfragB[2];
#pragma unroll
    for (int qhl = 0; qhl < 2; ++qhl)
        qfragB[qhl] = (quad == 0)
            ? *(const short8*)(qbuf + ((size_t)b * PP + q0 + qhl * 16 + col) * 8)
            : zf;

    floatx4 acc[2][4];
#pragma unroll
    for (int qhl = 0; qhl < 2; ++qhl)
#pragma unroll
        for (int cb = 0; cb < 4; ++cb) acc[qhl][cb] = (floatx4){0.f, 0.f, 0.f, 0.f};
    floatx4 accLh[2];
#pragma unroll
    for (int qhl = 0; qhl < 2; ++qhl) accLh[qhl] = (floatx4){0.f, 0.f, 0.f, 0.f};

    const ushort* kB = kbuf + (size_t)b * PP * 8;
    const ushort* vB = vfw + (size_t)b * 64 * PP;
    const int kwbase = g * keysPerG;

    // per-lane staging geometry: lane covers (row-in-8-group vr, chunk_pos lane&7)
    const int vr = lane >> 3;                 // 0..7
    const int vc = (lane & 7) ^ vr;           // swizzled logical chunk for this slot

    auto stage = [&](int t) {
        const int kw = kwbase + t * 64;
        char* Vb = sbuf + 9216 * (t % 3);
        // K: 64 rows x 16B; ALL 4 waves issue it (same bytes) so each wave's
        // per-stage gload count is exactly 3 (vmcnt accounting).
        gload16_lds(kB + (size_t)(kw + lane) * 8, Vb + 8192);
#pragma unroll
        for (int j = 0; j < 2; ++j) {
            const int jj = wid * 2 + j;                            // V group 0..7
            const int r  = jj * 8 + vr;                            // ch row 0..63
            gload16_lds(vB + (size_t)r * PP + kw + vc * 8, Vb + jj * 1024);
        }
    };

    auto compute = [&](int t) {
        const char* Vb = sbuf + 9216 * (t % 3);
        const ushort* Kl = (const ushort*)(Vb + 8192);
        // K A-operand rows = this wave's 32 keys; quads broadcast (slots >=8
        // multiply Q zeros).
        const short8 kf0 = *(const short8*)(Kl + (kh * 32 + col) * 8);
        const short8 kf1 = *(const short8*)(Kl + (kh * 32 + 16 + col) * 8);
        short8 vf[4];
        const int ce = (kh * 4 + quad) ^ (col & 7);   // swizzled chunk to read
#pragma unroll
        for (int cb = 0; cb < 4; ++cb)
            vf[cb] = *(const short8*)(Vb + ((cb * 16 + col) * 8 + ce) * 16);

#pragma unroll
        for (int qhl = 0; qhl < 2; ++qhl) {
            const floatx4 E0 = __builtin_amdgcn_mfma_f32_16x16x32_bf16(
                kf0, qfragB[qhl], (floatx4){0.f, 0.f, 0.f, 0.f}, 0, 0, 0);
            const floatx4 E1 = __builtin_amdgcn_mfma_f32_16x16x32_bf16(
                kf1, qfragB[qhl], (floatx4){0.f, 0.f, 0.f, 0.f}, 0, 0, 0);

            // Schraudolph bf16 P, packed pairs (slots quad*8 + 0..7)
            intx4 pi;
            pi.x = (int)exp2_pk_bf16(E0[0], E0[1]);
            pi.y = (int)exp2_pk_bf16(E0[2], E0[3]);
            pi.z = (int)exp2_pk_bf16(E1[0], E1[1]);
            pi.w = (int)exp2_pk_bf16(E1[2], E1[3]);
            const short8 pf = __builtin_bit_cast(short8, pi);

            // lsum on the matrix pipe: D[r][c] = sum_k P[k][c] for every r.
            accLh[qhl] = __builtin_amdgcn_mfma_f32_16x16x32_bf16(vones, pf, accLh[qhl], 0, 0, 0);
#pragma unroll
            for (int cb = 0; cb < 4; ++cb)
                acc[qhl][cb] = __builtin_amdgcn_mfma_f32_16x16x32_bf16(
                    vf[cb], pf, acc[qhl][cb], 0, 0, 0);
        }
    };

    // ---- 3-buffer counted-vmcnt main loop ----
    stage(0);
    stage(1);                                   // outstanding: 6 per wave
    for (int t = 0; t < numTiles - 1; ++t) {
        asm volatile("s_waitcnt vmcnt(3)" ::: "memory");   // stage(t) landed
        __builtin_amdgcn_s_barrier();                      // all 4 waves agree
        __builtin_amdgcn_sched_barrier(0);
        if (t + 2 < numTiles) stage(t + 2);                // buf[(t+2)%3]
        compute(t);
    }
    asm volatile("s_waitcnt vmcnt(0)" ::: "memory");       // last stage landed
    __builtin_amdgcn_s_barrier();
    __builtin_amdgcn_sched_barrier(0);
    compute(numTiles - 1);
    __syncthreads();            // all buf reads done before smerge overlay

    // ---- merge the two key-halves per q-half via LDS; kh==0 stores ----
    if (kh == 1) {
#pragma unroll
        for (int qhl = 0; qhl < 2; ++qhl)
#pragma unroll
            for (int cb = 0; cb < 4; ++cb)
#pragma unroll
                for (int r = 0; r < 4; ++r)
                    smerge[((size_t)qh2 * 64 + cb * 16 + quad * 4 + r) * 32
                           + qhl * 16 + col] = acc[qhl][cb][r];
        if (quad == 0)
#pragma unroll
            for (int qhl = 0; qhl < 2; ++qhl)
                slsum[qh2 * 32 + qhl * 16 + col] = accLh[qhl][0];
    }
    __syncthreads();
    if (kh == 0) {
        ushort* ab = accp + ((size_t)g * BB + b) * CC * PP;
#pragma unroll
        for (int qhl = 0; qhl < 2; ++qhl)
#pragma unroll
            for (int cb = 0; cb < 4; ++cb)
#pragma unroll
                for (int r = 0; r < 4; ++r) {
                    const int c = cb * 16 + quad * 4 + r;
                    const float v = acc[qhl][cb][r]
                        + smerge[((size_t)qh2 * 64 + c) * 32 + qhl * 16 + col];
                    ab[(size_t)c * PP + q0 + qhl * 16 + col] = f2bf(v);
                }
        if (quad == 0) {
            float* lb = lsump + ((size_t)g * BB + b) * PP + q0;
#pragma unroll
            for (int qhl = 0; qhl < 2; ++qhl)
                lb[qhl * 16 + col] = accLh[qhl][0]
                    + slsum[qh2 * 32 + qhl * 16 + col];
        }
    }
}

// ---------------------------------------------------------------------------
// Kernel 3: combine G partials, normalize, + gamma*attn + x. 576 x 256,
// 8 consecutive pixels per thread (layouts already [b][c][p]-major).
// ---------------------------------------------------------------------------
__global__ __launch_bounds__(256)
void combine(const ushort* __restrict__ accp, const float* __restrict__ lsump,
             const float* __restrict__ x, const float* __restrict__ gamma,
             float* __restrict__ out, int G)
{
    const size_t i8 = ((size_t)blockIdx.x * 256 + threadIdx.x) * 8;
    const int b = (int)(i8 / ((size_t)CC * PP));
    const int p = (int)(i8 % PP);
    const float gm = gamma[0];

    float asum[8] = {}, lst[8] = {};
    for (int g = 0; g < G; ++g) {
        const uint4 av = *(const uint4*)(accp + (size_t)g * (BB * CC * PP) + i8);
        const unsigned int u[4] = {av.x, av.y, av.z, av.w};
#pragma unroll
        for (int k = 0; k < 4; ++k) {
            asum[2 * k]     += __uint_as_float(u[k] << 16);
            asum[2 * k + 1] += __uint_as_float(u[k] & 0xffff0000u);
        }
        const float* lp = lsump + ((size_t)g * BB + b) * PP + p;
        const float4 l0 = *(const float4*)lp;
        const float4 l1 = *(const float4*)(lp + 4);
        lst[0] += l0.x; lst[1] += l0.y; lst[2] += l0.z; lst[3] += l0.w;
        lst[4] += l1.x; lst[5] += l1.y; lst[6] += l1.z; lst[7] += l1.w;
    }

    const float4 x0 = *(const float4*)(x + i8);
    const float4 x1 = *(const float4*)(x + i8 + 4);
    float o[8] = {x0.x, x0.y, x0.z, x0.w, x1.x, x1.y, x1.z, x1.w};
#pragma unroll
    for (int j = 0; j < 8; ++j)
        o[j] = fmaf(asum[j], gm / fmaxf(lst[j], 1e-30f), o[j]);
    *(float4*)(out + i8)     = make_float4(o[0], o[1], o[2], o[3]);
    *(float4*)(out + i8 + 4) = make_float4(o[4], o[5], o[6], o[7]);
}

// ---------------------------------------------------------------------------
extern "C" void kernel_launch(void* const* d_in, const int* in_sizes, int n_in,
                              void* d_out, int out_size, void* d_ws, size_t ws_size,
                              hipStream_t stream)
{
    const float* x     = (const float*)d_in[0];
    const float* Wq    = (const float*)d_in[1];
    const float* bq    = (const float*)d_in[2];
    const float* Wk    = (const float*)d_in[3];
    const float* bk    = (const float*)d_in[4];
    const float* Wv    = (const float*)d_in[5];
    const float* bv    = (const float*)d_in[6];
    const float* gamma = (const float*)d_in[7];
    float* out = (float*)d_out;

    // ws: qbuf | kbuf | vfw (bf16) | accp (bf16, G slots) | lsump (f32)
    const size_t nQK  = (size_t)BB * PP * 8;        // elems
    const size_t nV   = (size_t)BB * CC * PP;
    // G=4 fixed: g*BB+b spans exactly 8 values = 8 XCDs (attn14 swizzle).
    const int G = 4;
    const int keysPerG = PP / G;
    const int numTiles = keysPerG / 64;             // 36

    ushort* qbuf = (ushort*)d_ws;
    ushort* kbuf = qbuf + nQK;
    ushort* vfw  = kbuf + nQK;
    ushort* accp = vfw + nV;
    float* lsump = (float*)(accp + (size_t)G * nV);
    (void)ws_size;

    proj6<<<dim3(BB * 4 * QTILES), dim3(256), 0, stream>>>(
        x, Wq, bq, Wk, bk, Wv, bv, qbuf, kbuf, vfw);
    attn14<<<dim3(QTILES * 8), dim3(256), 0, stream>>>(
        qbuf, kbuf, vfw, accp, lsump, keysPerG, numTiles);
    combine<<<dim3(576), dim3(256), 0, stream>>>(
        accp, lsump, x, gamma, out, G);
}

// Round 12
// 118.189 us; speedup vs baseline: 1.0097x; 1.0097x over previous
//
#include <hip/hip_runtime.h>
#include <hip/hip_bf16.h>
#include <stdint.h>

// B,C,H,W = 2,64,96,96. Inputs fp32, output fp32.
// Budget: attn 42.5µs, proj ~3µs, combine ~8µs, fixed harness ~65µs.
// proj6 (round-9, verbatim): chunked c-loop + 4 row-blocks -> ~3µs.
// attn15: 128-key tiles (2x 64-key sub-tiles per barrier) to amortize the
//        ~1700cy/tile fixed overhead that survived pipeline-depth (r6), L2
//        locality (r7) and 2x TLP (r10, occupancy 15->23%, time identical).
//        2 buffers x 18KB (V sub0 8KB | V sub1 8KB | K 2KB); drain-vmcnt(0)
//        -> barrier -> stage(t+1) -> compute(t) (stage-after-barrier makes
//        the 2-buffer WAR safe; the drain is free since stage(t) was issued
//        one full double-tile earlier). 4 waves = (key-half, q-half); V
//        XOR-swizzle, ones-MFMA lsum, XCD remap qt*8+(g*BB+b) all retained.
// (Round-11 resubmit: identical source; previous run died to a container
// acquisition failure with no kernel verdict. Hang audit: uniform barriers,
// per-wave vmcnt drain, disjoint 2-buffer R/W, LDS 37.1KB x4 <= 160KB.)
// combine: sum G key-split partials, normalize, + gamma*attn + x.
#define BB 2
#define CC 64
#define PP 9216
#define QTILES 144               // PP/64
#define LOG2E 1.4426950408889634f
// big-constant Schraudolph: low16(E*128 + 16248.665 + 1.5*2^23) = bf16 bits of 2^E
#define SCH_BC 12599160.0f

typedef unsigned short ushort;
typedef __attribute__((ext_vector_type(8))) short short8;
typedef __attribute__((ext_vector_type(4))) float floatx4;
typedef __attribute__((ext_vector_type(4))) int intx4;

__device__ __forceinline__ ushort f2bf(float f) {
    unsigned int u = __float_as_uint(f);
    u = (u + 0x7fffu + ((u >> 16) & 1u)) >> 16;   // RNE
    return (ushort)u;
}

// 2^e0, 2^e1 as packed bf16 pair: add-big-constant Schraudolph (no v_cvt),
// then one v_perm_b32 splices the two low16 halves.
__device__ __forceinline__ unsigned int exp2_pk_bf16(float e0, float e1) {
    const float t0 = fmaf(e0, 128.f, SCH_BC);
    const float t1 = fmaf(e1, 128.f, SCH_BC);
    // result bytes: [t0.b0, t0.b1, t1.b0, t1.b1]
    return __builtin_amdgcn_perm(__float_as_uint(t1), __float_as_uint(t0),
                                 0x05040100u);
}

__device__ __forceinline__ void gload16_lds(const void* g, void* lds_base) {
    __builtin_amdgcn_global_load_lds(
        (const __attribute__((address_space(1))) unsigned int*)g,
        (__attribute__((address_space(3))) unsigned int*)lds_base, 16, 0, 0);
}

// ---------------------------------------------------------------------------
// Kernel 1: QKV projection (round-9 proj6, verbatim). 1152 blocks x 256.
// ---------------------------------------------------------------------------
__global__ __launch_bounds__(256)
void proj6(const float* __restrict__ x,
           const float* __restrict__ Wq, const float* __restrict__ bq,
           const float* __restrict__ Wk, const float* __restrict__ bk,
           const float* __restrict__ Wv, const float* __restrict__ bv,
           ushort* __restrict__ qbuf, ushort* __restrict__ kbuf,
           ushort* __restrict__ vfw)
{
    const int tid = threadIdx.x;
    const int px  = tid & 63;
    const int og  = __builtin_amdgcn_readfirstlane(tid >> 6);  // 0..3, wave-uniform
    const int blk = blockIdx.x;
    const int b     = blk / (4 * QTILES);
    const int rem   = blk % (4 * QTILES);
    const int ptile = rem >> 2;
    const int rq    = rem & 3;
    const int p     = ptile * 64 + px;
    const int r0    = rq * 20 + og * 5;          // first of this thread's 5 rows

    const float* wr[5];
#pragma unroll
    for (int r = 0; r < 5; ++r) {
        const int row = r0 + r;
        wr[r] = (row < 8) ? (Wq + row * 64)
              : (row < 16) ? (Wk + (row - 8) * 64)
              : (Wv + (row - 16) * 64);
    }

    const float* xb = x + (size_t)b * 64 * PP + p;
    float acc[5] = {0.f, 0.f, 0.f, 0.f, 0.f};

#pragma unroll 1
    for (int c0 = 0; c0 < 64; c0 += 16) {
        float xv[16];
#pragma unroll
        for (int i = 0; i < 16; ++i)
            xv[i] = xb[(size_t)(c0 + i) * PP];
#pragma unroll
        for (int i = 0; i < 16; ++i) {
#pragma unroll
            for (int r = 0; r < 5; ++r)
                acc[r] = fmaf(wr[r][c0 + i], xv[i], acc[r]);
        }
    }

#pragma unroll
    for (int r = 0; r < 5; ++r) {
        const int row = r0 + r;
        if (row < 8) {
            const float v = (acc[r] + bq[row]) * LOG2E;
            qbuf[((size_t)b * PP + p) * 8 + row] = f2bf(v);
        } else if (row < 16) {
            const float v = acc[r] + bk[row - 8];
            kbuf[((size_t)b * PP + p) * 8 + (row - 8)] = f2bf(v);
        } else {
            const int co = row - 16;
            const float v = acc[r] + bv[co];
            const int pl = p & 31;     // slot permutation within 32-group
            const int ps = (p & ~31) | ((((pl >> 2) & 3) << 3) | (((pl >> 4) & 1) << 2) | (pl & 3));
            vfw[((size_t)b * 64 + co) * PP + ps] = f2bf(v);
        }
    }
}

// ---------------------------------------------------------------------------
// Kernel 2: LDS-staged MFMA flash attention, 128-key tiles, 2-buffer
// drain-vmcnt, 4-wave q-split, XCD-partitioned. Grid = QTILES*8 blocks of
// 256; blockIdx = qt*8 + gb, gb = g*BB+b. Wave wid: kh = wid&1, qh2 = wid>>1;
// per tile each wave computes 32q x 2x32keys (sub 0/1) x 64ch.
// Buffer (18432B): V sub0 8KB | V sub1 8KB | K 2KB (row r at K+r*16).
// V sub layout = 8 groups x 1KB, rows XOR-swizzled (slot pos = chunk^(r&7),
// swizzle pre-applied on the GLOBAL source; ds_read applies the same XOR).
// Stage (per wave): 4 V-gloads (groups wid*4..wid*4+3 across both subs);
// waves 0/1 each stage one 64-row K half. No count equalization needed --
// the loop waits with a full drain.
// Loop: vmcnt(0) [stage(t) landed: issued one full double-tile earlier]
// -> barrier [all waves' stage(t) landed AND compute(t-1) done -> safe to
// overwrite buf[(t+1)&1]] -> stage(t+1) -> compute both subs.
// QK: E = mfma(A=K, B=Q) -> D[key][q]; P = Schraudolph bf16 bits = PV
// B-operand (V key-permuted at proj); lsum = ones-row MFMA.
// Epilogue: smerge (16KB) overlays buf0 (last read at t=16, fenced by the
// post-loop syncthreads; final compute reads buf1).
// ---------------------------------------------------------------------------
__global__ __launch_bounds__(256, 4)
void attn15(const ushort* __restrict__ qbuf, const ushort* __restrict__ kbuf,
            const ushort* __restrict__ vfw,
            ushort* __restrict__ accp, float* __restrict__ lsump,
            int keysPerG, int numTiles)
{
    // 0..36864: 2x (V 16KB + K 2KB) | 36864..37120: slsum (2 qh x 32 f32)
    // smerge (16KB f32, [qh2*64+c][32q]) overlays 0..16384 after the loop.
    __shared__ __align__(16) char sbuf[37120];
    float* smerge = (float*)sbuf;
    float* slsum  = (float*)(sbuf + 36864);

    const int tid  = threadIdx.x;
    const int lane = tid & 63;
    const int wid  = tid >> 6;        // 0..3
    const int kh   = wid & 1;         // key half (within a 64-key sub-tile)
    const int qh2  = wid >> 1;        // q half
    const int col  = lane & 15;
    const int quad = lane >> 4;

    // XCD-aware decode: consecutive blockIdx round-robin across the 8 XCDs,
    // so gb = blockIdx & 7 pins each (g,b) key-slice to one XCD's L2.
    const int qt = blockIdx.x >> 3;   // 0..143
    const int gb = blockIdx.x & 7;    // 0..7 = g*BB+b
    const int b  = gb % BB;
    const int g  = gb / BB;
    const int q0 = qt * 64 + qh2 * 32;   // this wave's 32 q rows

    const short8 zf = {0, 0, 0, 0, 0, 0, 0, 0};
    const short vone = (short)0x3F80;                 // bf16 1.0
    const short8 vones = {vone, vone, vone, vone, vone, vone, vone, vone};

    // Q fragments (B-operand: B[k=d=quad*8+j][n=q=col]); only quad 0 real.
    short8 qfragB[2];
#pragma unroll
    for (int qhl = 0; qhl < 2; ++qhl)
        qfragB[qhl] = (quad == 0)
            ? *(const short8*)(qbuf + ((size_t)b * PP + q0 + qhl * 16 + col) * 8)
            : zf;

    floatx4 acc[2][4];
#pragma unroll
    for (int qhl = 0; qhl < 2; ++qhl)
#pragma unroll
        for (int cb = 0; cb < 4; ++cb) acc[qhl][cb] = (floatx4){0.f, 0.f, 0.f, 0.f};
    floatx4 accLh[2];
#pragma unroll
    for (int qhl = 0; qhl < 2; ++qhl) accLh[qhl] = (floatx4){0.f, 0.f, 0.f, 0.f};

    const ushort* kB = kbuf + (size_t)b * PP * 8;
    const ushort* vB = vfw + (size_t)b * 64 * PP;
    const int kwbase = g * keysPerG;

    // per-lane staging geometry: lane covers (row-in-8-group vr, chunk_pos lane&7)
    const int vr = lane >> 3;                 // 0..7
    const int vc = (lane & 7) ^ vr;           // swizzled logical chunk for this slot

    auto stage = [&](int t) {
        const int kw = kwbase + t * 128;
        char* Bb = sbuf + (t & 1) * 18432;
        // V: 16 groups of 1KB (jj = sub*8 + grp); wave handles jj = wid*4+j.
#pragma unroll
        for (int j = 0; j < 4; ++j) {
            const int jj  = wid * 4 + j;
            const int sub = jj >> 3;
            const int grp = jj & 7;
            const int r   = grp * 8 + vr;                          // ch row 0..63
            gload16_lds(vB + (size_t)r * PP + (kw + sub * 64) + vc * 8,
                        Bb + sub * 8192 + grp * 1024);
        }
        // K: 128 rows x 16B; wave 0 -> rows 0..63, wave 1 -> rows 64..127.
        if (wid < 2)
            gload16_lds(kB + (size_t)(kw + wid * 64 + lane) * 8,
                        Bb + 16384 + wid * 1024);
    };

    auto computeSub = [&](const char* Bb, int sub) {
        const ushort* Kl = (const ushort*)(Bb + 16384 + sub * 1024);
        const char*   Vs = Bb + sub * 8192;
        // K A-operand rows = this wave's 32 keys of the sub; quads broadcast
        // (slots >=8 multiply Q zeros).
        const short8 kf0 = *(const short8*)(Kl + (kh * 32 + col) * 8);
        const short8 kf1 = *(const short8*)(Kl + (kh * 32 + 16 + col) * 8);
        short8 vf[4];
        const int ce = (kh * 4 + quad) ^ (col & 7);   // swizzled chunk to read
#pragma unroll
        for (int cb = 0; cb < 4; ++cb)
            vf[cb] = *(const short8*)(Vs + ((cb * 16 + col) * 8 + ce) * 16);

#pragma unroll
        for (int qhl = 0; qhl < 2; ++qhl) {
            const floatx4 E0 = __builtin_amdgcn_mfma_f32_16x16x32_bf16(
                kf0, qfragB[qhl], (floatx4){0.f, 0.f, 0.f, 0.f}, 0, 0, 0);
            const floatx4 E1 = __builtin_amdgcn_mfma_f32_16x16x32_bf16(
                kf1, qfragB[qhl], (floatx4){0.f, 0.f, 0.f, 0.f}, 0, 0, 0);

            // Schraudolph bf16 P, packed pairs (slots quad*8 + 0..7)
            intx4 pi;
            pi.x = (int)exp2_pk_bf16(E0[0], E0[1]);
            pi.y = (int)exp2_pk_bf16(E0[2], E0[3]);
            pi.z = (int)exp2_pk_bf16(E1[0], E1[1]);
            pi.w = (int)exp2_pk_bf16(E1[2], E1[3]);
            const short8 pf = __builtin_bit_cast(short8, pi);

            // lsum on the matrix pipe: D[r][c] = sum_k P[k][c] for every r.
            accLh[qhl] = __builtin_amdgcn_mfma_f32_16x16x32_bf16(vones, pf, accLh[qhl], 0, 0, 0);
#pragma unroll
            for (int cb = 0; cb < 4; ++cb)
                acc[qhl][cb] = __builtin_amdgcn_mfma_f32_16x16x32_bf16(
                    vf[cb], pf, acc[qhl][cb], 0, 0, 0);
        }
    };

    // ---- 2-buffer drain-vmcnt main loop (128 keys per iteration) ----
    stage(0);
    for (int t = 0; t < numTiles; ++t) {
        asm volatile("s_waitcnt vmcnt(0)" ::: "memory");   // own stage(t) landed
        __builtin_amdgcn_s_barrier();    // everyone's stage(t) landed AND
                                         // compute(t-1) done -> buf[(t+1)&1] free
        __builtin_amdgcn_sched_barrier(0);
        if (t + 1 < numTiles) stage(t + 1);
        const char* Bb = sbuf + (t & 1) * 18432;
        computeSub(Bb, 0);
        computeSub(Bb, 1);
    }
    __syncthreads();            // all buf reads done before smerge overlay

    // ---- merge the two key-halves per q-half via LDS; kh==0 stores ----
    if (kh == 1) {
#pragma unroll
        for (int qhl = 0; qhl < 2; ++qhl)
#pragma unroll
            for (int cb = 0; cb < 4; ++cb)
#pragma unroll
                for (int r = 0; r < 4; ++r)
                    smerge[((size_t)qh2 * 64 + cb * 16 + quad * 4 + r) * 32
                           + qhl * 16 + col] = acc[qhl][cb][r];
        if (quad == 0)
#pragma unroll
            for (int qhl = 0; qhl < 2; ++qhl)
                slsum[qh2 * 32 + qhl * 16 + col] = accLh[qhl][0];
    }
    __syncthreads();
    if (kh == 0) {
        ushort* ab = accp + ((size_t)g * BB + b) * CC * PP;
#pragma unroll
        for (int qhl = 0; qhl < 2; ++qhl)
#pragma unroll
            for (int cb = 0; cb < 4; ++cb)
#pragma unroll
                for (int r = 0; r < 4; ++r) {
                    const int c = cb * 16 + quad * 4 + r;
                    const float v = acc[qhl][cb][r]
                        + smerge[((size_t)qh2 * 64 + c) * 32 + qhl * 16 + col];
                    ab[(size_t)c * PP + q0 + qhl * 16 + col] = f2bf(v);
                }
        if (quad == 0) {
            float* lb = lsump + ((size_t)g * BB + b) * PP + q0;
#pragma unroll
            for (int qhl = 0; qhl < 2; ++qhl)
                lb[qhl * 16 + col] = accLh[qhl][0]
                    + slsum[qh2 * 32 + qhl * 16 + col];
        }
    }
}

// ---------------------------------------------------------------------------
// Kernel 3: combine G partials, normalize, + gamma*attn + x. 576 x 256,
// 8 consecutive pixels per thread (layouts already [b][c][p]-major).
// ---------------------------------------------------------------------------
__global__ __launch_bounds__(256)
void combine(const ushort* __restrict__ accp, const float* __restrict__ lsump,
             const float* __restrict__ x, const float* __restrict__ gamma,
             float* __restrict__ out, int G)
{
    const size_t i8 = ((size_t)blockIdx.x * 256 + threadIdx.x) * 8;
    const int b = (int)(i8 / ((size_t)CC * PP));
    const int p = (int)(i8 % PP);
    const float gm = gamma[0];

    float asum[8] = {}, lst[8] = {};
    for (int g = 0; g < G; ++g) {
        const uint4 av = *(const uint4*)(accp + (size_t)g * (BB * CC * PP) + i8);
        const unsigned int u[4] = {av.x, av.y, av.z, av.w};
#pragma unroll
        for (int k = 0; k < 4; ++k) {
            asum[2 * k]     += __uint_as_float(u[k] << 16);
            asum[2 * k + 1] += __uint_as_float(u[k] & 0xffff0000u);
        }
        const float* lp = lsump + ((size_t)g * BB + b) * PP + p;
        const float4 l0 = *(const float4*)lp;
        const float4 l1 = *(const float4*)(lp + 4);
        lst[0] += l0.x; lst[1] += l0.y; lst[2] += l0.z; lst[3] += l0.w;
        lst[4] += l1.x; lst[5] += l1.y; lst[6] += l1.z; lst[7] += l1.w;
    }

    const float4 x0 = *(const float4*)(x + i8);
    const float4 x1 = *(const float4*)(x + i8 + 4);
    float o[8] = {x0.x, x0.y, x0.z, x0.w, x1.x, x1.y, x1.z, x1.w};
#pragma unroll
    for (int j = 0; j < 8; ++j)
        o[j] = fmaf(asum[j], gm / fmaxf(lst[j], 1e-30f), o[j]);
    *(float4*)(out + i8)     = make_float4(o[0], o[1], o[2], o[3]);
    *(float4*)(out + i8 + 4) = make_float4(o[4], o[5], o[6], o[7]);
}

// ---------------------------------------------------------------------------
extern "C" void kernel_launch(void* const* d_in, const int* in_sizes, int n_in,
                              void* d_out, int out_size, void* d_ws, size_t ws_size,
                              hipStream_t stream)
{
    const float* x     = (const float*)d_in[0];
    const float* Wq    = (const float*)d_in[1];
    const float* bq    = (const float*)d_in[2];
    const float* Wk    = (const float*)d_in[3];
    const float* bk    = (const float*)d_in[4];
    const float* Wv    = (const float*)d_in[5];
    const float* bv    = (const float*)d_in[6];
    const float* gamma = (const float*)d_in[7];
    float* out = (float*)d_out;

    // ws: qbuf | kbuf | vfw (bf16) | accp (bf16, G slots) | lsump (f32)
    const size_t nQK  = (size_t)BB * PP * 8;        // elems
    const size_t nV   = (size_t)BB * CC * PP;
    // G=4 fixed: g*BB+b spans exactly 8 values = 8 XCDs (attn15 swizzle).
    const int G = 4;
    const int keysPerG = PP / G;
    const int numTiles = keysPerG / 128;            // 18

    ushort* qbuf = (ushort*)d_ws;
    ushort* kbuf = qbuf + nQK;
    ushort* vfw  = kbuf + nQK;
    ushort* accp = vfw + nV;
    float* lsump = (float*)(accp + (size_t)G * nV);
    (void)ws_size;

    proj6<<<dim3(BB * 4 * QTILES), dim3(256), 0, stream>>>(
        x, Wq, bq, Wk, bk, Wv, bv, qbuf, kbuf, vfw);
    attn15<<<dim3(QTILES * 8), dim3(256), 0, stream>>>(
        qbuf, kbuf, vfw, accp, lsump, keysPerG, numTiles);
    combine<<<dim3(576), dim3(256), 0, stream>>>(
        accp, lsump, x, gamma, out, G);
}

// Round 13
// 117.622 us; speedup vs baseline: 1.0146x; 1.0048x over previous
//
#include <hip/hip_runtime.h>
#include <hip/hip_bf16.h>
#include <stdint.h>

// B,C,H,W = 2,64,96,96. Inputs fp32, output fp32.
// Budget (r12 discovery): harness ws-fill 40.8µs (268MB fillBufferAligned,
// untouchable) + misc memsets/launch ~24µs + attn ~40µs + combine ~8µs +
// proj ~3µs = ~118. Kernels are only 51µs of the total.
// proj6 (round-9, verbatim): chunked c-loop + 4 row-blocks -> ~3µs.
// attn16: = attn15 (128-key tiles, 2-buffer drain-vmcnt, 4-wave q-split,
//        XOR-swizzled V, ones-MFMA lsum) with G=2 key-split: halves accp
//        WRITE (9504->4752KB) and combine's read stream. XCD decode
//        gb = blockIdx&3: XCD x (= blk%8) serves only slice x&3 -> 0.8MB
//        working set per XCD L2, preserving the r7 FETCH collapse.
//        Grid = QTILES*4 = 576 blocks of 256; numTiles = 36 (128-key).
// combine: sum 2 key-split partials, normalize, + gamma*attn + x (~19MB).
#define BB 2
#define CC 64
#define PP 9216
#define QTILES 144               // PP/64
#define LOG2E 1.4426950408889634f
// big-constant Schraudolph: low16(E*128 + 16248.665 + 1.5*2^23) = bf16 bits of 2^E
#define SCH_BC 12599160.0f

typedef unsigned short ushort;
typedef __attribute__((ext_vector_type(8))) short short8;
typedef __attribute__((ext_vector_type(4))) float floatx4;
typedef __attribute__((ext_vector_type(4))) int intx4;

__device__ __forceinline__ ushort f2bf(float f) {
    unsigned int u = __float_as_uint(f);
    u = (u + 0x7fffu + ((u >> 16) & 1u)) >> 16;   // RNE
    return (ushort)u;
}

// 2^e0, 2^e1 as packed bf16 pair: add-big-constant Schraudolph (no v_cvt),
// then one v_perm_b32 splices the two low16 halves.
__device__ __forceinline__ unsigned int exp2_pk_bf16(float e0, float e1) {
    const float t0 = fmaf(e0, 128.f, SCH_BC);
    const float t1 = fmaf(e1, 128.f, SCH_BC);
    // result bytes: [t0.b0, t0.b1, t1.b0, t1.b1]
    return __builtin_amdgcn_perm(__float_as_uint(t1), __float_as_uint(t0),
                                 0x05040100u);
}

__device__ __forceinline__ void gload16_lds(const void* g, void* lds_base) {
    __builtin_amdgcn_global_load_lds(
        (const __attribute__((address_space(1))) unsigned int*)g,
        (__attribute__((address_space(3))) unsigned int*)lds_base, 16, 0, 0);
}

// ---------------------------------------------------------------------------
// Kernel 1: QKV projection (round-9 proj6, verbatim). 1152 blocks x 256.
// ---------------------------------------------------------------------------
__global__ __launch_bounds__(256)
void proj6(const float* __restrict__ x,
           const float* __restrict__ Wq, const float* __restrict__ bq,
           const float* __restrict__ Wk, const float* __restrict__ bk,
           const float* __restrict__ Wv, const float* __restrict__ bv,
           ushort* __restrict__ qbuf, ushort* __restrict__ kbuf,
           ushort* __restrict__ vfw)
{
    const int tid = threadIdx.x;
    const int px  = tid & 63;
    const int og  = __builtin_amdgcn_readfirstlane(tid >> 6);  // 0..3, wave-uniform
    const int blk = blockIdx.x;
    const int b     = blk / (4 * QTILES);
    const int rem   = blk % (4 * QTILES);
    const int ptile = rem >> 2;
    const int rq    = rem & 3;
    const int p     = ptile * 64 + px;
    const int r0    = rq * 20 + og * 5;          // first of this thread's 5 rows

    const float* wr[5];
#pragma unroll
    for (int r = 0; r < 5; ++r) {
        const int row = r0 + r;
        wr[r] = (row < 8) ? (Wq + row * 64)
              : (row < 16) ? (Wk + (row - 8) * 64)
              : (Wv + (row - 16) * 64);
    }

    const float* xb = x + (size_t)b * 64 * PP + p;
    float acc[5] = {0.f, 0.f, 0.f, 0.f, 0.f};

#pragma unroll 1
    for (int c0 = 0; c0 < 64; c0 += 16) {
        float xv[16];
#pragma unroll
        for (int i = 0; i < 16; ++i)
            xv[i] = xb[(size_t)(c0 + i) * PP];
#pragma unroll
        for (int i = 0; i < 16; ++i) {
#pragma unroll
            for (int r = 0; r < 5; ++r)
                acc[r] = fmaf(wr[r][c0 + i], xv[i], acc[r]);
        }
    }

#pragma unroll
    for (int r = 0; r < 5; ++r) {
        const int row = r0 + r;
        if (row < 8) {
            const float v = (acc[r] + bq[row]) * LOG2E;
            qbuf[((size_t)b * PP + p) * 8 + row] = f2bf(v);
        } else if (row < 16) {
            const float v = acc[r] + bk[row - 8];
            kbuf[((size_t)b * PP + p) * 8 + (row - 8)] = f2bf(v);
        } else {
            const int co = row - 16;
            const float v = acc[r] + bv[co];
            const int pl = p & 31;     // slot permutation within 32-group
            const int ps = (p & ~31) | ((((pl >> 2) & 3) << 3) | (((pl >> 4) & 1) << 2) | (pl & 3));
            vfw[((size_t)b * 64 + co) * PP + ps] = f2bf(v);
        }
    }
}

// ---------------------------------------------------------------------------
// Kernel 2: LDS-staged MFMA flash attention, 128-key tiles, 2-buffer
// drain-vmcnt, 4-wave q-split, XCD-partitioned, G=2. Grid = QTILES*4 blocks
// of 256; blockIdx = qt*4 + gb, gb = g*BB+b in 0..3. XCD x = blk%8 sees only
// gb = x&3 -> one key-slice per XCD L2 (~0.8MB). Wave wid: kh = wid&1,
// qh2 = wid>>1; per tile each wave computes 32q x 2x32keys (sub 0/1) x 64ch.
// Buffer (18432B): V sub0 8KB | V sub1 8KB | K 2KB. V sub = 8 groups x 1KB,
// rows XOR-swizzled (slot pos = chunk^(r&7), pre-applied on the GLOBAL
// source; ds_read applies the same XOR).
// Stage (per wave): 4 V-gloads (groups wid*4..wid*4+3); waves 0/1 each stage
// one 64-row K half. Loop: vmcnt(0) [own stage(t) landed; issued one full
// double-tile earlier] -> barrier [all stages landed AND compute(t-1) done
// -> buf[(t+1)&1] free] -> stage(t+1) -> compute both subs.
// QK: E = mfma(A=K, B=Q) -> D[key][q]; P = Schraudolph bf16 bits = PV
// B-operand (V key-permuted at proj); lsum = ones-row MFMA.
// Epilogue: smerge (16KB) overlays buf0 (fenced by post-loop syncthreads).
// ---------------------------------------------------------------------------
__global__ __launch_bounds__(256, 4)
void attn16(const ushort* __restrict__ qbuf, const ushort* __restrict__ kbuf,
            const ushort* __restrict__ vfw,
            ushort* __restrict__ accp, float* __restrict__ lsump,
            int keysPerG, int numTiles)
{
    // 0..36864: 2x (V 16KB + K 2KB) | 36864..37120: slsum (2 qh x 32 f32)
    // smerge (16KB f32, [qh2*64+c][32q]) overlays 0..16384 after the loop.
    __shared__ __align__(16) char sbuf[37120];
    float* smerge = (float*)sbuf;
    float* slsum  = (float*)(sbuf + 36864);

    const int tid  = threadIdx.x;
    const int lane = tid & 63;
    const int wid  = tid >> 6;        // 0..3
    const int kh   = wid & 1;         // key half (within a 64-key sub-tile)
    const int qh2  = wid >> 1;        // q half
    const int col  = lane & 15;
    const int quad = lane >> 4;

    // XCD-aware decode: blk%8 = XCD; gb = blk&3 -> XCD x serves slice x&3.
    const int qt = blockIdx.x >> 2;   // 0..143
    const int gb = blockIdx.x & 3;    // 0..3 = g*BB+b
    const int b  = gb % BB;
    const int g  = gb / BB;           // 0..1
    const int q0 = qt * 64 + qh2 * 32;   // this wave's 32 q rows

    const short8 zf = {0, 0, 0, 0, 0, 0, 0, 0};
    const short vone = (short)0x3F80;                 // bf16 1.0
    const short8 vones = {vone, vone, vone, vone, vone, vone, vone, vone};

    // Q fragments (B-operand: B[k=d=quad*8+j][n=q=col]); only quad 0 real.
    short8 qfragB[2];
#pragma unroll
    for (int qhl = 0; qhl < 2; ++qhl)
        qfragB[qhl] = (quad == 0)
            ? *(const short8*)(qbuf + ((size_t)b * PP + q0 + qhl * 16 + col) * 8)
            : zf;

    floatx4 acc[2][4];
#pragma unroll
    for (int qhl = 0; qhl < 2; ++qhl)
#pragma unroll
        for (int cb = 0; cb < 4; ++cb) acc[qhl][cb] = (floatx4){0.f, 0.f, 0.f, 0.f};
    floatx4 accLh[2];
#pragma unroll
    for (int qhl = 0; qhl < 2; ++qhl) accLh[qhl] = (floatx4){0.f, 0.f, 0.f, 0.f};

    const ushort* kB = kbuf + (size_t)b * PP * 8;
    const ushort* vB = vfw + (size_t)b * 64 * PP;
    const int kwbase = g * keysPerG;

    // per-lane staging geometry: lane covers (row-in-8-group vr, chunk_pos lane&7)
    const int vr = lane >> 3;                 // 0..7
    const int vc = (lane & 7) ^ vr;           // swizzled logical chunk for this slot

    auto stage = [&](int t) {
        const int kw = kwbase + t * 128;
        char* Bb = sbuf + (t & 1) * 18432;
        // V: 16 groups of 1KB (jj = sub*8 + grp); wave handles jj = wid*4+j.
#pragma unroll
        for (int j = 0; j < 4; ++j) {
            const int jj  = wid * 4 + j;
            const int sub = jj >> 3;
            const int grp = jj & 7;
            const int r   = grp * 8 + vr;                          // ch row 0..63
            gload16_lds(vB + (size_t)r * PP + (kw + sub * 64) + vc * 8,
                        Bb + sub * 8192 + grp * 1024);
        }
        // K: 128 rows x 16B; wave 0 -> rows 0..63, wave 1 -> rows 64..127.
        if (wid < 2)
            gload16_lds(kB + (size_t)(kw + wid * 64 + lane) * 8,
                        Bb + 16384 + wid * 1024);
    };

    auto computeSub = [&](const char* Bb, int sub) {
        const ushort* Kl = (const ushort*)(Bb + 16384 + sub * 1024);
        const char*   Vs = Bb + sub * 8192;
        // K A-operand rows = this wave's 32 keys of the sub; quads broadcast
        // (slots >=8 multiply Q zeros).
        const short8 kf0 = *(const short8*)(Kl + (kh * 32 + col) * 8);
        const short8 kf1 = *(const short8*)(Kl + (kh * 32 + 16 + col) * 8);
        short8 vf[4];
        const int ce = (kh * 4 + quad) ^ (col & 7);   // swizzled chunk to read
#pragma unroll
        for (int cb = 0; cb < 4; ++cb)
            vf[cb] = *(const short8*)(Vs + ((cb * 16 + col) * 8 + ce) * 16);

#pragma unroll
        for (int qhl = 0; qhl < 2; ++qhl) {
            const floatx4 E0 = __builtin_amdgcn_mfma_f32_16x16x32_bf16(
                kf0, qfragB[qhl], (floatx4){0.f, 0.f, 0.f, 0.f}, 0, 0, 0);
            const floatx4 E1 = __builtin_amdgcn_mfma_f32_16x16x32_bf16(
                kf1, qfragB[qhl], (floatx4){0.f, 0.f, 0.f, 0.f}, 0, 0, 0);

            // Schraudolph bf16 P, packed pairs (slots quad*8 + 0..7)
            intx4 pi;
            pi.x = (int)exp2_pk_bf16(E0[0], E0[1]);
            pi.y = (int)exp2_pk_bf16(E0[2], E0[3]);
            pi.z = (int)exp2_pk_bf16(E1[0], E1[1]);
            pi.w = (int)exp2_pk_bf16(E1[2], E1[3]);
            const short8 pf = __builtin_bit_cast(short8, pi);

            // lsum on the matrix pipe: D[r][c] = sum_k P[k][c] for every r.
            accLh[qhl] = __builtin_amdgcn_mfma_f32_16x16x32_bf16(vones, pf, accLh[qhl], 0, 0, 0);
#pragma unroll
            for (int cb = 0; cb < 4; ++cb)
                acc[qhl][cb] = __builtin_amdgcn_mfma_f32_16x16x32_bf16(
                    vf[cb], pf, acc[qhl][cb], 0, 0, 0);
        }
    };

    // ---- 2-buffer drain-vmcnt main loop (128 keys per iteration) ----
    stage(0);
    for (int t = 0; t < numTiles; ++t) {
        asm volatile("s_waitcnt vmcnt(0)" ::: "memory");   // own stage(t) landed
        __builtin_amdgcn_s_barrier();    // everyone's stage(t) landed AND
                                         // compute(t-1) done -> buf[(t+1)&1] free
        __builtin_amdgcn_sched_barrier(0);
        if (t + 1 < numTiles) stage(t + 1);
        const char* Bb = sbuf + (t & 1) * 18432;
        computeSub(Bb, 0);
        computeSub(Bb, 1);
    }
    __syncthreads();            // all buf reads done before smerge overlay

    // ---- merge the two key-halves per q-half via LDS; kh==0 stores ----
    if (kh == 1) {
#pragma unroll
        for (int qhl = 0; qhl < 2; ++qhl)
#pragma unroll
            for (int cb = 0; cb < 4; ++cb)
#pragma unroll
                for (int r = 0; r < 4; ++r)
                    smerge[((size_t)qh2 * 64 + cb * 16 + quad * 4 + r) * 32
                           + qhl * 16 + col] = acc[qhl][cb][r];
        if (quad == 0)
#pragma unroll
            for (int qhl = 0; qhl < 2; ++qhl)
                slsum[qh2 * 32 + qhl * 16 + col] = accLh[qhl][0];
    }
    __syncthreads();
    if (kh == 0) {
        ushort* ab = accp + ((size_t)g * BB + b) * CC * PP;
#pragma unroll
        for (int qhl = 0; qhl < 2; ++qhl)
#pragma unroll
            for (int cb = 0; cb < 4; ++cb)
#pragma unroll
                for (int r = 0; r < 4; ++r) {
                    const int c = cb * 16 + quad * 4 + r;
                    const float v = acc[qhl][cb][r]
                        + smerge[((size_t)qh2 * 64 + c) * 32 + qhl * 16 + col];
                    ab[(size_t)c * PP + q0 + qhl * 16 + col] = f2bf(v);
                }
        if (quad == 0) {
            float* lb = lsump + ((size_t)g * BB + b) * PP + q0;
#pragma unroll
            for (int qhl = 0; qhl < 2; ++qhl)
                lb[qhl * 16 + col] = accLh[qhl][0]
                    + slsum[qh2 * 32 + qhl * 16 + col];
        }
    }
}

// ---------------------------------------------------------------------------
// Kernel 3: combine G=2 partials, normalize, + gamma*attn + x. 576 x 256,
// 8 consecutive pixels per thread (layouts already [b][c][p]-major).
// ---------------------------------------------------------------------------
__global__ __launch_bounds__(256)
void combine(const ushort* __restrict__ accp, const float* __restrict__ lsump,
             const float* __restrict__ x, const float* __restrict__ gamma,
             float* __restrict__ out, int G)
{
    const size_t i8 = ((size_t)blockIdx.x * 256 + threadIdx.x) * 8;
    const int b = (int)(i8 / ((size_t)CC * PP));
    const int p = (int)(i8 % PP);
    const float gm = gamma[0];

    float asum[8] = {}, lst[8] = {};
    for (int g = 0; g < G; ++g) {
        const uint4 av = *(const uint4*)(accp + (size_t)g * (BB * CC * PP) + i8);
        const unsigned int u[4] = {av.x, av.y, av.z, av.w};
#pragma unroll
        for (int k = 0; k < 4; ++k) {
            asum[2 * k]     += __uint_as_float(u[k] << 16);
            asum[2 * k + 1] += __uint_as_float(u[k] & 0xffff0000u);
        }
        const float* lp = lsump + ((size_t)g * BB + b) * PP + p;
        const float4 l0 = *(const float4*)lp;
        const float4 l1 = *(const float4*)(lp + 4);
        lst[0] += l0.x; lst[1] += l0.y; lst[2] += l0.z; lst[3] += l0.w;
        lst[4] += l1.x; lst[5] += l1.y; lst[6] += l1.z; lst[7] += l1.w;
    }

    const float4 x0 = *(const float4*)(x + i8);
    const float4 x1 = *(const float4*)(x + i8 + 4);
    float o[8] = {x0.x, x0.y, x0.z, x0.w, x1.x, x1.y, x1.z, x1.w};
#pragma unroll
    for (int j = 0; j < 8; ++j)
        o[j] = fmaf(asum[j], gm / fmaxf(lst[j], 1e-30f), o[j]);
    *(float4*)(out + i8)     = make_float4(o[0], o[1], o[2], o[3]);
    *(float4*)(out + i8 + 4) = make_float4(o[4], o[5], o[6], o[7]);
}

// ---------------------------------------------------------------------------
extern "C" void kernel_launch(void* const* d_in, const int* in_sizes, int n_in,
                              void* d_out, int out_size, void* d_ws, size_t ws_size,
                              hipStream_t stream)
{
    const float* x     = (const float*)d_in[0];
    const float* Wq    = (const float*)d_in[1];
    const float* bq    = (const float*)d_in[2];
    const float* Wk    = (const float*)d_in[3];
    const float* bk    = (const float*)d_in[4];
    const float* Wv    = (const float*)d_in[5];
    const float* bv    = (const float*)d_in[6];
    const float* gamma = (const float*)d_in[7];
    float* out = (float*)d_out;

    // ws: qbuf | kbuf | vfw (bf16) | accp (bf16, G slots) | lsump (f32)
    const size_t nQK  = (size_t)BB * PP * 8;        // elems
    const size_t nV   = (size_t)BB * CC * PP;
    // G=2: g*BB+b spans 4 values; XCD x (=blk%8) serves slice x&3.
    const int G = 2;
    const int keysPerG = PP / G;                    // 4608
    const int numTiles = keysPerG / 128;            // 36

    ushort* qbuf = (ushort*)d_ws;
    ushort* kbuf = qbuf + nQK;
    ushort* vfw  = kbuf + nQK;
    ushort* accp = vfw + nV;
    float* lsump = (float*)(accp + (size_t)G * nV);
    (void)ws_size;

    proj6<<<dim3(BB * 4 * QTILES), dim3(256), 0, stream>>>(
        x, Wq, bq, Wk, bk, Wv, bv, qbuf, kbuf, vfw);
    attn16<<<dim3(QTILES * 4), dim3(256), 0, stream>>>(
        qbuf, kbuf, vfw, accp, lsump, keysPerG, numTiles);
    combine<<<dim3(576), dim3(256), 0, stream>>>(
        accp, lsump, x, gamma, out, G);
}